// Round 1
// baseline (93.284 us; speedup 1.0000x reference)
//
#include <hip/hip_runtime.h>

// Vanilla RNN B=4096 S=512 I=1 H=16 O=1 — serial-chain latency optimization.
// Lane = (batch, h-row); 16 lanes/batch; 1024 waves = 1 wave/SIMD, one
// serial chain per SIMD. Wall = 512 * (F + T) per chain, independent of
// wave packing (R11 measured: 2 chains/wave at half the waves = exactly
// 2x wall). F = front issue span, T = tail dep chain.
//
// R13 = R12 with the tail critical path shortened by one VALU link:
//   old: a1 -> v_add(s=a0+a1) -> v_exp -> v_add(e+1) -> v_rcp -> g
//   new: a1 -> v_exp(a1) -> v_fma(e0,e1,1.0) -> v_rcp -> g
// using exp2(a0+a1) = exp2(a0)*exp2(a1); exp2(a0) issues while a1's
// chain drains (a0 retires ~2 instrs earlier), and the +1.0 folds into
// the product via VOP3 inline-constant fma. Same op count (4 tail ops),
// one fewer serial dependency. a0,a1 individually bounded (|s|<~18, so
// e<=2^18 — no overflow risk in the split exponentials).
//
// Front kept verbatim from R12: 2 interleaved accumulator chains of
// depth 8. Hazard-proven head kept verbatim (s_nop 1, a0 tied to XP
// computed OUTSIDE the asm, plain fmac before the first DPP read of g —
// R8/R9-style head restructure is the known 8.8e-3 corruption, never do
// it). Same-chain fmacs are 2 instrs apart (~6 cyc) >= fmac dep latency.
//
// g-trick: state g = 1/(2^s+1), h = 1-2g; rowsum(W_hh) folds into bias,
// -2*S2LE into weights; S2LE = 2*log2(e) pre-scales for exp2.
// Weights self-calibrated to the HW row_ror permutation (R1/R7-validated).
// Loads: R6 staged blocks, modulo-2 named buffers, no per-iter vmcnt drain.

#define S2LE 2.8853900817779268f  // 2*log2(e)

typedef float float4_ __attribute__((ext_vector_type(4)));

#define ROTI(v, N) __builtin_amdgcn_mov_dpp((v), 0x120 + (N), 0xF, 0xF, 0)
#define ROTF(v, N) __int_as_float(__builtin_amdgcn_mov_dpp(__float_as_int(v), 0x120 + (N), 0xF, 0xF, 0))

__global__ __launch_bounds__(64) void rnn_kernel(
    const float* __restrict__ x,
    const float* __restrict__ W_ih,
    const float* __restrict__ W_hh,
    const float* __restrict__ b_ih,
    const float* __restrict__ b_hh,
    const float* __restrict__ W_fc,
    const float* __restrict__ b_fc,
    float* __restrict__ out)
{
    const int li = (int)(threadIdx.x & 15u);
    const int b  = (int)((blockIdx.x * 64u + threadIdx.x) >> 4);

    const float* __restrict__ row = W_hh + li * 16;

    float sw = 0.0f;
#pragma unroll
    for (int j = 0; j < 16; ++j) sw += row[j];

    const float wsc = -2.0f * S2LE;

    // Self-calibrated weights: w[N] = wsc * W[li][sigma_N(li)], sigma_N =
    // the HW's row_ror:N permutation (validated end-to-end R1/R7).
    float w0  = wsc * row[li];
    float w1  = wsc * row[ROTI(li, 1)];
    float w2  = wsc * row[ROTI(li, 2)];
    float w3  = wsc * row[ROTI(li, 3)];
    float w4  = wsc * row[ROTI(li, 4)];
    float w5  = wsc * row[ROTI(li, 5)];
    float w6  = wsc * row[ROTI(li, 6)];
    float w7  = wsc * row[ROTI(li, 7)];
    float w8  = wsc * row[ROTI(li, 8)];
    float w9  = wsc * row[ROTI(li, 9)];
    float w10 = wsc * row[ROTI(li, 10)];
    float w11 = wsc * row[ROTI(li, 11)];
    float w12 = wsc * row[ROTI(li, 12)];
    float w13 = wsc * row[ROTI(li, 13)];
    float w14 = wsc * row[ROTI(li, 14)];
    float w15 = wsc * row[ROTI(li, 15)];

    const float wih  = W_ih[li] * S2LE;
    const float bias = (b_ih[li] + b_hh[li] + sw) * S2LE;
    const float wfc  = W_fc[li];
    const float bfc  = b_fc[0];

    const float4_* __restrict__ xv = (const float4_*)(x + (size_t)b * 512);

    float g = 0.5f;  // represents h = 0

    // One step: R7 head (s_nop 1, tied a0=XP, plain fmac first), then 2
    // interleaved DPP-fmac chains of depth 8; split-exp2 tail:
    //   e0 = exp2(a0) (issues early, hides under a1 drain)
    //   e1 = exp2(a1); g = rcp(fma(e0, e1, 1.0))
    // (best measured tails: R5 poly +93, R8 newton +17 cyc/step — keep
    // exp2+rcp; R13 removes the pre-exp add from the serial chain.)
#define STEP(XP) do { \
    float a0 = (XP), a1; \
    asm volatile( \
        "s_nop 1\n\t" \
        "v_fmac_f32 %0, %2, %3\n\t" \
        "v_mul_f32_dpp %1, %2, %11  row_ror:8  row_mask:0xf bank_mask:0xf\n\t" \
        "v_fmac_f32_dpp %0, %2, %4  row_ror:1  row_mask:0xf bank_mask:0xf\n\t" \
        "v_fmac_f32_dpp %1, %2, %12 row_ror:9  row_mask:0xf bank_mask:0xf\n\t" \
        "v_fmac_f32_dpp %0, %2, %5  row_ror:2  row_mask:0xf bank_mask:0xf\n\t" \
        "v_fmac_f32_dpp %1, %2, %13 row_ror:10 row_mask:0xf bank_mask:0xf\n\t" \
        "v_fmac_f32_dpp %0, %2, %6  row_ror:3  row_mask:0xf bank_mask:0xf\n\t" \
        "v_fmac_f32_dpp %1, %2, %14 row_ror:11 row_mask:0xf bank_mask:0xf\n\t" \
        "v_fmac_f32_dpp %0, %2, %7  row_ror:4  row_mask:0xf bank_mask:0xf\n\t" \
        "v_fmac_f32_dpp %1, %2, %15 row_ror:12 row_mask:0xf bank_mask:0xf\n\t" \
        "v_fmac_f32_dpp %0, %2, %8  row_ror:5  row_mask:0xf bank_mask:0xf\n\t" \
        "v_fmac_f32_dpp %1, %2, %16 row_ror:13 row_mask:0xf bank_mask:0xf\n\t" \
        "v_fmac_f32_dpp %0, %2, %9  row_ror:6  row_mask:0xf bank_mask:0xf\n\t" \
        "v_fmac_f32_dpp %1, %2, %17 row_ror:14 row_mask:0xf bank_mask:0xf\n\t" \
        "v_fmac_f32_dpp %0, %2, %10 row_ror:7  row_mask:0xf bank_mask:0xf\n\t" \
        "v_fmac_f32_dpp %1, %2, %18 row_ror:15 row_mask:0xf bank_mask:0xf\n\t" \
        : "+v"(a0), "=&v"(a1) \
        : "v"(g), \
          "v"(w0),  "v"(w1),  "v"(w2),  "v"(w3), \
          "v"(w4),  "v"(w5),  "v"(w6),  "v"(w7), \
          "v"(w8),  "v"(w9),  "v"(w10), "v"(w11), \
          "v"(w12), "v"(w13), "v"(w14), "v"(w15)); \
    float e0_ = __builtin_amdgcn_exp2f(a0); \
    float e1_ = __builtin_amdgcn_exp2f(a1); \
    g = __builtin_amdgcn_rcpf(fmaf(e0_, e1_, 1.0f)); \
} while (0)

// 16 recurrent steps from a 4-x-float4 staged block.
#define BLOCK(BUF) do { \
    _Pragma("unroll") \
    for (int j = 0; j < 4; ++j) { \
        STEP(fmaf((BUF)[j][0], wih, bias)); \
        STEP(fmaf((BUF)[j][1], wih, bias)); \
        STEP(fmaf((BUF)[j][2], wih, bias)); \
        STEP(fmaf((BUF)[j][3], wih, bias)); \
    } \
} while (0)

    float4_ bufA[4], bufB[4];
#pragma unroll
    for (int j = 0; j < 4; ++j) bufA[j] = xv[j];  // block 0

    // Unroll-2 modulo pipeline over 32 blocks of 16 timesteps (R6): loads
    // issue one full block ahead; no register rotation, no per-iter drain.
#pragma unroll 1
    for (int i = 0; i < 32; i += 2) {
#pragma unroll
        for (int j = 0; j < 4; ++j) bufB[j] = xv[(4 * (i + 1) + j) & 127];
        BLOCK(bufA);
#pragma unroll
        for (int j = 0; j < 4; ++j) bufA[j] = xv[(4 * (i + 2) + j) & 127];
        BLOCK(bufB);
    }
#undef BLOCK
#undef STEP

    // out[b] = sum_i wfc_i * h_i + bfc,  h = 1 - 2g (f32 g).
    float p = fmaf(-2.0f * wfc, g, wfc);
    p += ROTF(p, 8);
    p += ROTF(p, 4);
    p += ROTF(p, 2);
    p += ROTF(p, 1);
    if (li == 0) out[b] = p + bfc;
}

extern "C" void kernel_launch(void* const* d_in, const int* in_sizes, int n_in,
                              void* d_out, int out_size, void* d_ws, size_t ws_size,
                              hipStream_t stream) {
    const float* x    = (const float*)d_in[0];
    const float* W_ih = (const float*)d_in[1];
    const float* W_hh = (const float*)d_in[2];
    const float* b_ih = (const float*)d_in[3];
    const float* b_hh = (const float*)d_in[4];
    const float* W_fc = (const float*)d_in[5];
    const float* b_fc = (const float*)d_in[6];
    float* out = (float*)d_out;

    rnn_kernel<<<1024, 64, 0, stream>>>(x, W_ih, W_hh, b_ih, b_hh, W_fc, b_fc, out);
}